// Round 4
// baseline (1041.770 us; speedup 1.0000x reference)
//
#include <hip/hip_runtime.h>
#include <hip/hip_bf16.h>

typedef unsigned short u16;
typedef unsigned int u32;
typedef __attribute__((ext_vector_type(8))) short short8;
typedef __attribute__((ext_vector_type(4))) float floatx4;
typedef __attribute__((ext_vector_type(4))) unsigned short ushort4v;
typedef __attribute__((ext_vector_type(8))) unsigned short ushort8v;

#define NWIN 2048
#define NTOK 49
#define NH 16
#define HDIM 32
#define CDIM 512
#define MTOT (NWIN * NTOK)   /* 100352 */
#define NOUT (3 * CDIM)      /* 1536 */
#define KDIM CDIM            /* 512 */

__device__ inline float b2f(u16 u) {
    unsigned int x = ((unsigned int)u) << 16;
    float f; __builtin_memcpy(&f, &x, 4); return f;
}
__device__ inline u16 f2b(float f) {
    unsigned int u; __builtin_memcpy(&u, &f, 4);
    unsigned int r = (u + 0x7fffu + ((u >> 16) & 1u)) >> 16;
    return (u16)r;
}
__device__ inline void gload16(const void* g, void* l) {
    __builtin_amdgcn_global_load_lds((const __attribute__((address_space(1))) unsigned int*)g,
                                     (__attribute__((address_space(3))) unsigned int*)l, 16, 0, 0);
}

// ---------------- prep: fp32 -> bf16 convert of hidden_states ----------------
__global__ void k_cvt_x(const float4* __restrict__ x, ushort4v* __restrict__ xb, int n4) {
    int i = blockIdx.x * blockDim.x + threadIdx.x;
    int stride = gridDim.x * blockDim.x;
    for (; i < n4; i += stride) {
        float4 v = x[i];
        ushort4v o = { f2b(v.x), f2b(v.y), f2b(v.z), f2b(v.w) };
        xb[i] = o;
    }
}

// ---------------- prep: pack Wqkv (bf16 [1536,512]) + bias (fp32 [1536]) -----
__global__ void k_pack_w(const float* __restrict__ wq, const float* __restrict__ wk,
                         const float* __restrict__ wv, const float* __restrict__ bq,
                         const float* __restrict__ bk, const float* __restrict__ bv,
                         u16* __restrict__ wout, float* __restrict__ bout) {
    const int WN = CDIM * CDIM; // 262144
    int i = blockIdx.x * blockDim.x + threadIdx.x;
    if (i < 3 * WN) {
        const float* src = (i < WN) ? wq : (i < 2 * WN ? wk : wv);
        wout[i] = f2b(src[i & (WN - 1)]);
    }
    if (i < 3 * CDIM) {
        const float* sb = (i < CDIM) ? bq : (i < 2 * CDIM ? bk : bv);
        bout[i] = sb[i & (CDIM - 1)];
    }
}

// ------- prep: padded bias+mask bmT[w*16+h][i(query) 64][j(key) 64] ----------
__global__ void k_bmT(const float* __restrict__ mask, const float* __restrict__ bt,
                      float* __restrict__ bmT) {
    int t = blockIdx.x;          // 0..1023
    int w = t >> 4, h = t & 15;
    float* dst = bmT + (size_t)t * 4096;
    const float* mw = mask + (size_t)w * 2401;
    for (int e = threadIdx.x; e < 4096; e += blockDim.x) {
        int i = e >> 6, j = e & 63;
        float v;
        if (j >= 49) v = -1.0e30f;
        else if (i >= 49) v = 0.f;
        else {
            int ri = i / 7, ci = i - ri * 7;
            int rj = j / 7, cj = j - rj * 7;
            int idx = (ri - rj + 6) * 13 + (ci - cj + 6);
            v = bt[idx * 16 + h] + mw[i * 49 + j];
        }
        dst[e] = v;
    }
}

// ---------------- QKV projection GEMM: [100352,512] x [1536,512]^T -----------
__global__ __launch_bounds__(256)
void k_gemm(const u16* __restrict__ A, const u16* __restrict__ Bw,
            const float* __restrict__ bias, u16* __restrict__ C) {
    __shared__ __align__(16) u16 As[128 * 32];
    __shared__ __align__(16) u16 Bs[128 * 32];
    const int tid = threadIdx.x;
    const int lane = tid & 63;
    const int wave = tid >> 6;
    const int n0 = blockIdx.x * 128;
    const int m0 = blockIdx.y * 128;
    const int mh = (wave & 1) * 64;
    const int nh = (wave >> 1) * 64;

    floatx4 acc[4][4];
#pragma unroll
    for (int mi = 0; mi < 4; mi++)
#pragma unroll
        for (int ni = 0; ni < 4; ni++)
            acc[mi][ni] = (floatx4){0.f, 0.f, 0.f, 0.f};

    const int rA1 = tid >> 2, c1 = tid & 3;
    const int rA2 = rA1 + 64;
    const int cg1 = c1 ^ ((rA1 >> 1) & 3);
    const int cg2 = c1 ^ ((rA2 >> 1) & 3);
    const u16* pa1 = A + (size_t)(m0 + rA1) * KDIM + cg1 * 8;
    const u16* pa2 = A + (size_t)(m0 + rA2) * KDIM + cg2 * 8;
    const u16* pb1 = Bw + (size_t)(n0 + rA1) * KDIM + cg1 * 8;
    const u16* pb2 = Bw + (size_t)(n0 + rA2) * KDIM + cg2 * 8;
    u16* la1 = &As[tid * 8];
    u16* la2 = &As[(tid + 256) * 8];
    u16* lb1 = &Bs[tid * 8];
    u16* lb2 = &Bs[(tid + 256) * 8];

    int aoff[4], boff[4];
    const int quad = lane >> 4;
#pragma unroll
    for (int mi = 0; mi < 4; mi++) {
        int r = mh + mi * 16 + (lane & 15);
        aoff[mi] = r * 32 + (quad ^ ((r >> 1) & 3)) * 8;
        int rn = nh + mi * 16 + (lane & 15);
        boff[mi] = rn * 32 + (quad ^ ((rn >> 1) & 3)) * 8;
    }

    for (int ks = 0; ks < 16; ++ks) {
        const int k0 = ks * 32;
        gload16(pa1 + k0, la1);
        gload16(pa2 + k0, la2);
        gload16(pb1 + k0, lb1);
        gload16(pb2 + k0, lb2);
        __syncthreads();
        short8 af[4], bf[4];
#pragma unroll
        for (int mi = 0; mi < 4; mi++) af[mi] = *(const short8*)&As[aoff[mi]];
#pragma unroll
        for (int ni = 0; ni < 4; ni++) bf[ni] = *(const short8*)&Bs[boff[ni]];
#pragma unroll
        for (int mi = 0; mi < 4; mi++)
#pragma unroll
            for (int ni = 0; ni < 4; ni++)
                acc[mi][ni] = __builtin_amdgcn_mfma_f32_16x16x32_bf16(af[mi], bf[ni], acc[mi][ni], 0, 0, 0);
        __syncthreads();
    }

    const int colc = lane & 15;
#pragma unroll
    for (int ni = 0; ni < 4; ni++) {
        int gn = n0 + nh + ni * 16 + colc;
        float bv_ = bias[gn];
#pragma unroll
        for (int mi = 0; mi < 4; mi++) {
            size_t gmb = (size_t)(m0 + mh + mi * 16 + quad * 4);
#pragma unroll
            for (int r = 0; r < 4; r++)
                C[(gmb + r) * NOUT + gn] = f2b(acc[mi][ni][r] + bv_);
        }
    }
}

// -------- HYBRID attention (bisect): MFMA QK^T+softmax, VALU PV --------------
// Stage 1 identical to round 2/3 (inv folded into P pack). Stage 2 is
// round-1's verified VALU consumer reading P from LDS. Pass => stage-2 MFMA
// path was the bug. Fail => stage 1 is.
__global__ __launch_bounds__(256)
void k_attn(const u16* __restrict__ qkv, const float* __restrict__ bmT,
            float* __restrict__ out) {
    __shared__ __align__(16) u16 Pl[4][4096];          // P[i][j] bf16, swizzled
    __shared__ __align__(16) float Vsb[4][NTOK * HDIM]; // V fp32, round-1 layout
    const int lane = threadIdx.x & 63;
    const int wave = threadIdx.x >> 6;
    const int l15 = lane & 15;
    const int quad = lane >> 4;
    const int task = blockIdx.x * 4 + wave;  // 0..32767
    const int b = task >> 4;
    const int h = task & 15;
    const size_t rowbase = (size_t)b * NTOK * NOUT;
    const u16* basep = qkv + rowbase + h * 32 + quad * 8;

    // ---- stage V into LDS fp32 (round-1 verified code) ----
    float* Vs = Vsb[wave];
    for (int i = lane; i < 392; i += 64) {
        int n = i >> 3;
        int dq = (i & 7) * 4;
        const u16* vp0 = qkv + rowbase + (size_t)n * NOUT + 1024 + h * 32 + dq;
        ushort4v vv = *(const ushort4v*)vp0;
#pragma unroll
        for (int z = 0; z < 4; z++) Vs[n * 32 + dq + z] = b2f(vv[z]);
    }

    // ---- stage 1: S^T = K·Q^T via MFMA ----
    short8 kf[4], qf[4];
#pragma unroll
    for (int mt = 0; mt < 4; mt++) {
        int j = mt * 16 + l15; j = j > 48 ? 48 : j;
        kf[mt] = *(const short8*)(basep + (size_t)j * NOUT + 512);
    }
#pragma unroll
    for (int nt = 0; nt < 4; nt++) {
        int i = nt * 16 + l15; i = i > 48 ? 48 : i;
        qf[nt] = *(const short8*)(basep + (size_t)i * NOUT);
    }
    floatx4 acc[4][4];   // S^T: row j = mt*16+quad*4+r, col i = nt*16+l15
#pragma unroll
    for (int mt = 0; mt < 4; mt++)
#pragma unroll
        for (int nt = 0; nt < 4; nt++)
            acc[mt][nt] = __builtin_amdgcn_mfma_f32_16x16x32_bf16(
                kf[mt], qf[nt], (floatx4){0.f, 0.f, 0.f, 0.f}, 0, 0, 0);

    const float* bmt = bmT + (size_t)((b & 63) * 16 + h) * 4096;
    const float scale = 0.17677669529663687f;
#pragma unroll
    for (int nt = 0; nt < 4; nt++) {
        const int i = nt * 16 + l15;
#pragma unroll
        for (int mt = 0; mt < 4; mt++) {
            floatx4 bm4 = *(const floatx4*)(bmt + i * 64 + mt * 16 + quad * 4);
#pragma unroll
            for (int r = 0; r < 4; r++)
                acc[mt][nt][r] = acc[mt][nt][r] * scale + bm4[r];
        }
    }

    // softmax over j: in-lane (mt,r) + cross-quad shuffles; fold inv into P
    float inv[4];
#pragma unroll
    for (int nt = 0; nt < 4; nt++) {
        float mx = -3.0e38f;
#pragma unroll
        for (int mt = 0; mt < 4; mt++)
#pragma unroll
            for (int r = 0; r < 4; r++) mx = fmaxf(mx, acc[mt][nt][r]);
        mx = fmaxf(mx, __shfl_xor(mx, 16));
        mx = fmaxf(mx, __shfl_xor(mx, 32));
        float sm = 0.f;
#pragma unroll
        for (int mt = 0; mt < 4; mt++)
#pragma unroll
            for (int r = 0; r < 4; r++) {
                float e = __expf(acc[mt][nt][r] - mx);
                acc[mt][nt][r] = e;
                sm += e;
            }
        sm += __shfl_xor(sm, 16);
        sm += __shfl_xor(sm, 32);
        inv[nt] = 1.0f / sm;
    }

    // pack normalized P to bf16 -> LDS, chunk-XOR swizzle
    u16* pw = Pl[wave];
#pragma unroll
    for (int nt = 0; nt < 4; nt++) {
        const int i = nt * 16 + l15;
        const int ix = i & 7;
#pragma unroll
        for (int mt = 0; mt < 4; mt++) {
            u32 u0 = __builtin_bit_cast(u32, acc[mt][nt][0] * inv[nt]);
            u32 u1 = __builtin_bit_cast(u32, acc[mt][nt][1] * inv[nt]);
            u32 u2 = __builtin_bit_cast(u32, acc[mt][nt][2] * inv[nt]);
            u32 u3 = __builtin_bit_cast(u32, acc[mt][nt][3] * inv[nt]);
            uint2 val;
            val.x = (u0 >> 16) | (u1 & 0xffff0000u);
            val.y = (u2 >> 16) | (u3 & 0xffff0000u);
            int j0 = mt * 16 + quad * 4;
            int addr = i * 64 + ((((j0 >> 3) ^ ix)) << 3) + (j0 & 7);
            *(uint2*)&pw[addr] = val;
        }
    }
    __syncthreads();

    // ---- stage 2: round-1 VALU PV (lane = query row) ----
    const int irow = lane < 49 ? lane : 48;
    const int ixr = irow & 7;
    float o[32];
#pragma unroll
    for (int d = 0; d < 32; d++) o[d] = 0.f;
#pragma unroll
    for (int j = 0; j < 49; j++) {
        float pj = b2f(pw[irow * 64 + ((((j >> 3) ^ ixr)) << 3) + (j & 7)]);
        const floatx4* vr = (const floatx4*)(Vs + j * 32);
#pragma unroll
        for (int dq = 0; dq < 8; dq++) {
            floatx4 vv = vr[dq];
            o[dq * 4 + 0] += pj * vv[0];
            o[dq * 4 + 1] += pj * vv[1];
            o[dq * 4 + 2] += pj * vv[2];
            o[dq * 4 + 3] += pj * vv[3];
        }
    }
    if (lane < 49) {
        float* op = out + ((size_t)(b * 49 + lane)) * CDIM + h * 32;
#pragma unroll
        for (int dq = 0; dq < 8; dq++) {
            floatx4 res = { o[dq * 4 + 0], o[dq * 4 + 1], o[dq * 4 + 2], o[dq * 4 + 3] };
            *(floatx4*)(op + dq * 4) = res;
        }
    }
}

extern "C" void kernel_launch(void* const* d_in, const int* in_sizes, int n_in,
                              void* d_out, int out_size, void* d_ws, size_t ws_size,
                              hipStream_t stream) {
    const float* hs   = (const float*)d_in[0];
    const float* mask = (const float*)d_in[1];
    const float* wq   = (const float*)d_in[2];
    const float* bq   = (const float*)d_in[3];
    const float* wk   = (const float*)d_in[4];
    const float* bk   = (const float*)d_in[5];
    const float* wv   = (const float*)d_in[6];
    const float* bv   = (const float*)d_in[7];
    const float* bt   = (const float*)d_in[8];
    float* out = (float*)d_out;

    // bf16 X lives in d_out (dead until k_attn's final stores)
    u16* xb = (u16*)d_out;

    char* ws = (char*)d_ws;
    size_t off = 0;
    u16* wb = (u16*)(ws + off);      off += (size_t)NOUT * KDIM * 2;       // 1.5 MB
    float* biasb = (float*)(ws + off); off += (size_t)NOUT * 4;
    off = (off + 255) & ~(size_t)255;
    float* bmT = (float*)(ws + off); off += (size_t)1024 * 4096 * 4;       // 16.8 MB
    off = (off + 255) & ~(size_t)255;
    u16* qkv = (u16*)(ws + off);     off += (size_t)MTOT * NOUT * 2;       // 308 MB

    k_cvt_x<<<4096, 256, 0, stream>>>((const float4*)hs, (ushort4v*)xb, MTOT * CDIM / 4);
    k_pack_w<<<3072, 256, 0, stream>>>(wq, wk, wv, bq, bk, bv, wb, biasb);
    k_bmT<<<1024, 256, 0, stream>>>(mask, bt, bmT);
    k_gemm<<<dim3(12, 784), 256, 0, stream>>>(xb, wb, biasb, qkv);
    k_attn<<<8192, 256, 0, stream>>>(qkv, bmT, out);
}